// Round 5
// baseline (255.003 us; speedup 1.0000x reference)
//
#include <hip/hip_runtime.h>

// FieldAwareFMLayer: x (bs, 40, 39, 16) fp32.
// out[n] = sum_{0<=i<=j<=38} dot(x[n,i,j,:], x[n,j+1,i,:])
//
// 204.5 MB exactly-once read => HBM-bound, floor ~33 us.
// R4 (batched loads + arithmetic index decode) fixed the MLP/latency bound.
// R5 adds: all HBM traffic contiguous. The b operands (lower wedge, stride
// 2496 B between needed 64B lines = DRAM row thrash) are instead loaded by
// PACKED slot order (contiguous global runs), parked in registers, written
// to LDS; partners are then fetched from LDS. The a operands (upper wedge)
// are contiguous runs already. All 14 global loads issue back-to-back
// before the single barrier.

#define NF 40
#define NC 39
#define ED 16
#define NPAIRS 780
#define ROW_FLOATS (NF * NC * ED)     // 24960 floats per batch row
#define NTASKS (NPAIRS * 4)           // one float4 partial-dot per task = 3120
#define NTH 512
#define TRIPS ((NTASKS + NTH - 1) / NTH)   // 7

typedef float f32x4 __attribute__((ext_vector_type(4)));

__global__ __launch_bounds__(NTH) void ffm_interact_kernel(
        const float* __restrict__ x, float* __restrict__ out) {
    __shared__ f32x4 ldsb[NPAIRS * 4];     // 49920 B packed lower wedge
    const int n = blockIdx.x;
    const int tid = threadIdx.x;
    const int q = tid & 3;                 // quad within embedding
    const int p0 = tid >> 2;               // task-pair base; p_k = p0 + 128k
    const f32x4* __restrict__ base4 =
        (const f32x4*)(x + (size_t)n * ROW_FLOATS);

    // ---- pure-VALU index decode (no memory dependency) ----
    int aoff[TRIPS];   // upper-wedge global f32x4 offset (pair order)
    int soff[TRIPS];   // LDS slot f32x4 offset of the partner (pair order)
    int goff[TRIPS];   // lower-wedge global f32x4 offset (packed slot order)
    #pragma unroll
    for (int k = 0; k < TRIPS; ++k) {
        int p = p0 + 128 * k;
        p = p < NPAIRS ? p : (NPAIRS - 1);           // clamp tail (masked)
        // pair p -> (i,j), j>=i  : i = floor((79-sqrt(6241-8p))/2), guarded
        const float dA = 6241.0f - 8.0f * (float)p;
        int i = (int)((79.0f - __builtin_sqrtf(dA)) * 0.5f);
        int Si = 39 * i - ((i * (i - 1)) >> 1);
        if (p < Si) { --i; Si = 39 * i - ((i * (i - 1)) >> 1); }
        else { const int Si1 = Si + (NC - i); if (p >= Si1) { ++i; Si = Si1; } }
        const int j = i + (p - Si);
        aoff[k] = (i * NC + j) * 4 + q;              // a = (i, j)
        soff[k] = (((j + 1) * j) >> 1) * 4 + q + i * 4;  // packed slot (j+1)j/2+i

        // packed slot s -> (g,c), c<g : g = floor((1+sqrt(1+8s))/2), guarded
        const int s = p;                              // same linear index space
        const float dB = 1.0f + 8.0f * (float)s;
        int g = (int)((1.0f + __builtin_sqrtf(dB)) * 0.5f);
        int Tg = (g * (g - 1)) >> 1;
        if (s < Tg) { --g; Tg = (g * (g - 1)) >> 1; }
        else if (s >= Tg + g) { ++g; Tg = (g * (g - 1)) >> 1; }
        const int c = s - Tg;
        goff[k] = (g * NC + c) * 4 + q;              // b source = (g, c)
    }

    // ---- batched global loads: lower wedge first, then upper wedge ----
    f32x4 bv[TRIPS], av[TRIPS];
    #pragma unroll
    for (int k = 0; k < TRIPS; ++k)
        bv[k] = __builtin_nontemporal_load(&base4[goff[k]]);
    #pragma unroll
    for (int k = 0; k < TRIPS; ++k)
        av[k] = __builtin_nontemporal_load(&base4[aoff[k]]);

    // ---- stage lower wedge into LDS in packed order ----
    #pragma unroll
    for (int k = 0; k < TRIPS; ++k) {
        int t = tid + k * NTH;
        int dst = t < NTASKS ? t : (NPAIRS - 1) * 4 + q;  // clamp = rewrite same data
        ldsb[dst] = bv[k];
    }
    __syncthreads();

    // ---- dot products against LDS-resident partners ----
    float acc = 0.0f;
    #pragma unroll
    for (int k = 0; k < TRIPS; ++k) {
        const f32x4 b = ldsb[soff[k]];
        const float m = ((tid + k * NTH) < NTASKS) ? 1.0f : 0.0f;
        acc = fmaf(m * av[k][0], b[0], acc);
        acc = fmaf(m * av[k][1], b[1], acc);
        acc = fmaf(m * av[k][2], b[2], acc);
        acc = fmaf(m * av[k][3], b[3], acc);
    }

    // wave-64 reduce, then cross-wave
    #pragma unroll
    for (int off = 32; off > 0; off >>= 1)
        acc += __shfl_down(acc, off, 64);

    __shared__ float wave_sum[NTH / 64];
    if ((tid & 63) == 0) wave_sum[tid >> 6] = acc;
    __syncthreads();
    if (tid == 0) {
        float s = 0.0f;
        #pragma unroll
        for (int w = 0; w < NTH / 64; ++w) s += wave_sum[w];
        out[n] = s;
    }
}

extern "C" void kernel_launch(void* const* d_in, const int* in_sizes, int n_in,
                              void* d_out, int out_size, void* d_ws, size_t ws_size,
                              hipStream_t stream) {
    const float* x = (const float*)d_in[0];
    float* out = (float*)d_out;
    const int bs = in_sizes[0] / ROW_FLOATS;   // 2048
    ffm_interact_kernel<<<bs, NTH, 0, stream>>>(x, out);
}